// Round 1
// baseline (334.238 us; speedup 1.0000x reference)
//
#include <hip/hip_runtime.h>

#define C_CH 16
#define Hdim 128
#define Wdim 128
#define HWdim 16384
#define CHW (C_CH * HWdim)                 // 262144 floats: one [C][H][W] slab
#define Bdim 2
#define PAIR_ELEMS (Bdim * CHW)            // 524288

// padded canvas geometry (border 3 = max P/2, zeroed once per launch)
#define HP 134
#define WP 136
#define PL (HP * WP)                       // 18224 elements per plane

typedef float v2f __attribute__((ext_vector_type(2)));
typedef _Float16 h2 __attribute__((ext_vector_type(2)));
typedef _Float16 f16x8 __attribute__((ext_vector_type(8)));
typedef float f32x4 __attribute__((ext_vector_type(4)));

__device__ __forceinline__ v2f unpack2(unsigned u) {
  h2 h = __builtin_bit_cast(h2, u);
  return (v2f){(float)h.x, (float)h.y};
}
__device__ __forceinline__ unsigned pack2(float a, float b) {
  h2 h = {(_Float16)a, (_Float16)b};
  return __builtin_bit_cast(unsigned, h);
}

// conflict-free LDS row strides (elements):
//  8x8 reads:  SR % 8 == 4;  16x4 reads: SR % 32 in {8,16,24}
template<int P> struct SimSR { static constexpr int v = (P == 7) ? 20 : 12; };

// ---------------------------------------------------------------------------
// Prep: memT[d][m] = mem * temp/sqrt(D)   (f32, m-contiguous)         [sim]
//       tg: memR[m][u][v][c]              (f32, kernel-flipped)       [read tg]
//       bg: whi/wlo[uv][c][m]             (f16 hi+lo split)           [read bg MFMA]
// ---------------------------------------------------------------------------
struct PrepDesc {
  const float* mem;
  const float* temp;
  float* memT;
  float* memR;          // tg only (else null)
  _Float16* whi;        // bg only (else null)
  _Float16* wlo;        // bg only (else null)
  int M, D, P;
};
struct PrepArgs { PrepDesc d[6]; };

__global__ __launch_bounds__(256) void k_prep(PrepArgs a) {
  PrepDesc de = a.d[blockIdx.y];
  int n = de.M * de.D;
  int idx = blockIdx.x * 256 + threadIdx.x;
  if (idx >= n) return;
  int m = idx / de.D;
  int d = idx - m * de.D;
  float val = de.mem[idx];
  float sc = de.temp[0] / sqrtf((float)de.D);
  de.memT[d * de.M + m] = val * sc;
  int pp = de.P * de.P;
  int c = d / pp;
  int r = d - c * pp;
  int i = r / de.P;
  int j = r - i * de.P;
  if (de.memR)
    de.memR[((m * de.P + (de.P - 1 - i)) * de.P + (de.P - 1 - j)) * C_CH + c] = val;
  if (de.whi) {
    int u = de.P - 1 - i, v = de.P - 1 - j;
    size_t widx = ((size_t)(u * de.P + v) * 16 + c) * 64 + m;
    _Float16 hi = (_Float16)val;
    de.whi[widx] = hi;
    de.wlo[widx] = (_Float16)(val - (float)hi);
  }
}

// ---------------------------------------------------------------------------
// Build f16 c-pair-packed padded canvas.
// ---------------------------------------------------------------------------
__global__ __launch_bounds__(256) void k_padx(const float* __restrict__ bg,
                                              const float* __restrict__ tg,
                                              unsigned* __restrict__ xpad2)
{
  int idx = blockIdx.x * 256 + threadIdx.x;     // 32 pair-planes * HW
  int pp = idx >> 14;
  int hw = idx & (HWdim - 1);
  int y = hw >> 7, x = hw & 127;
  int z = pp >> 3, cp = pp & 7;
  const float* src = (z < 2) ? bg : tg;
  int b = z & 1;
  float a = src[((b * C_CH + 2 * cp) << 14) + hw];
  float bb = src[((b * C_CH + 2 * cp + 1) << 14) + hw];
  xpad2[(size_t)pp * PL + (y + 3) * WP + (x + 3)] = pack2(a, bb);
}

// ---------------------------------------------------------------------------
// Sim conv + softmax.
// bg -> att pixel-major m-contiguous f16: attb[(y+3)*WP+x+3][m], m=0..63
// tg -> m-pair-packed f16 padded planes (unchanged layout)
// ---------------------------------------------------------------------------
template<int P>
__device__ __forceinline__ void sim_core_bg(
    const unsigned* __restrict__ xt2, float* __restrict__ red,
    const float* __restrict__ memT, unsigned* __restrict__ attb,
    int wv, int lane, int x0, int y0)
{
  constexpr int TH = 8 + P - 1, SR = SimSR<P>::v;
  constexpr int M = 64;
  const int px = lane & 7, py = lane >> 3;
  const int m0 = wv * 8;
  v2f acc2[4];
#pragma unroll
  for (int mm = 0; mm < 4; ++mm) acc2[mm] = (v2f){0.f, 0.f};

  for (int cp = 0; cp < 8; ++cp) {
#pragma unroll
    for (int i = 0; i < P; ++i) {
#pragma unroll
      for (int j = 0; j < P; ++j) {
        v2f vp = unpack2(xt2[(cp * TH + py + i) * SR + (px + j)]);
        const v2f* w0 = (const v2f*)(memT + (size_t)((((2 * cp) * P + i) * P + j)) * M + m0);
        const v2f* w1 = (const v2f*)(memT + (size_t)((((2 * cp + 1) * P + i) * P + j)) * M + m0);
        v2f v0 = {vp.x, vp.x}, v1 = {vp.y, vp.y};
#pragma unroll
        for (int mm = 0; mm < 4; ++mm) {
          acc2[mm] = __builtin_elementwise_fma(v0, w0[mm], acc2[mm]);
          acc2[mm] = __builtin_elementwise_fma(v1, w1[mm], acc2[mm]);
        }
      }
    }
  }

  float acc[8];
#pragma unroll
  for (int mm = 0; mm < 4; ++mm) { acc[2 * mm] = acc2[mm].x; acc[2 * mm + 1] = acc2[mm].y; }

  float pm = acc[0];
#pragma unroll
  for (int mm = 1; mm < 8; ++mm) pm = fmaxf(pm, acc[mm]);
  red[wv * 64 + lane] = pm;
  __syncthreads();
  float gm = red[lane];
#pragma unroll
  for (int w = 1; w < 8; ++w) gm = fmaxf(gm, red[w * 64 + lane]);
  __syncthreads();
  float ps = 0.f;
#pragma unroll
  for (int mm = 0; mm < 8; ++mm) { acc[mm] = __expf(acc[mm] - gm); ps += acc[mm]; }
  red[wv * 64 + lane] = ps;
  __syncthreads();
  float tot = 0.f;
#pragma unroll
  for (int w = 0; w < 8; ++w) tot += red[w * 64 + lane];
  float inv = 1.f / tot;

  const int gy = y0 + py, gx = x0 + px;
  unsigned p0 = pack2(acc[0] * inv, acc[1] * inv);
  unsigned p1 = pack2(acc[2] * inv, acc[3] * inv);
  unsigned p2 = pack2(acc[4] * inv, acc[5] * inv);
  unsigned p3 = pack2(acc[6] * inv, acc[7] * inv);
  uint4 st = {p0, p1, p2, p3};
  *(uint4*)(attb + ((size_t)(gy + 3) * WP + (gx + 3)) * 32 + wv * 4) = st;
}

template<int P>
__device__ __forceinline__ void sim_core_tg(
    const unsigned* __restrict__ xt2, float* __restrict__ red,  // [8][8][64]
    const float* __restrict__ memT, unsigned* __restrict__ att2,
    int wv, int lane, int x0, int y0)
{
  constexpr int TH = 8 + P - 1, SR = SimSR<P>::v;
  constexpr int M = 8;
  const int px = lane & 7, py = lane >> 3;
  const int cp = wv;
  v2f acc2[4];
#pragma unroll
  for (int mm = 0; mm < 4; ++mm) acc2[mm] = (v2f){0.f, 0.f};

#pragma unroll
  for (int i = 0; i < P; ++i) {
#pragma unroll
    for (int j = 0; j < P; ++j) {
      v2f vp = unpack2(xt2[(cp * TH + py + i) * SR + (px + j)]);
      const v2f* w0 = (const v2f*)(memT + (size_t)((((2 * cp) * P + i) * P + j)) * M);
      const v2f* w1 = (const v2f*)(memT + (size_t)((((2 * cp + 1) * P + i) * P + j)) * M);
      v2f v0 = {vp.x, vp.x}, v1 = {vp.y, vp.y};
#pragma unroll
      for (int mm = 0; mm < 4; ++mm) {
        acc2[mm] = __builtin_elementwise_fma(v0, w0[mm], acc2[mm]);
        acc2[mm] = __builtin_elementwise_fma(v1, w1[mm], acc2[mm]);
      }
    }
  }

#pragma unroll
  for (int mm = 0; mm < 4; ++mm) {
    red[(wv * 8 + 2 * mm) * 64 + lane]     = acc2[mm].x;
    red[(wv * 8 + 2 * mm + 1) * 64 + lane] = acc2[mm].y;
  }
  __syncthreads();

  float lg[8];
#pragma unroll
  for (int m = 0; m < 8; ++m) {
    float s = red[m * 64 + lane];
#pragma unroll
    for (int w = 1; w < 8; ++w) s += red[(w * 8 + m) * 64 + lane];
    lg[m] = s;
  }
  float gm = lg[0];
#pragma unroll
  for (int m = 1; m < 8; ++m) gm = fmaxf(gm, lg[m]);
  float tot = 0.f;
#pragma unroll
  for (int m = 0; m < 8; ++m) { lg[m] = __expf(lg[m] - gm); tot += lg[m]; }
  float inv = 1.f / tot;

  const int gy = y0 + py, gx = x0 + px;
  if (wv < 4)
    att2[(size_t)wv * PL + (gy + 3) * WP + (gx + 3)] =
        pack2(lg[2 * wv] * inv, lg[2 * wv + 1] * inv);
}

template<int P>
__global__ __launch_bounds__(512, 8) void k_sim(
    const unsigned* __restrict__ xpad2,
    const float* __restrict__ memTbg, const float* __restrict__ memTtg,
    unsigned* __restrict__ attbg,    // [2][PL][64] f16 (as u32 pairs)
    unsigned* __restrict__ atttg2)   // [2][4]  pair-planes
{
  constexpr int PAD = P / 2, TH = 8 + P - 1, SR = SimSR<P>::v;
  __shared__ unsigned xt2[8 * TH * SR];
  __shared__ float red[8 * 8 * 64];

  const int tid = threadIdx.x;
  const int wv = __builtin_amdgcn_readfirstlane(tid >> 6);
  const int lane = tid & 63;
  const int x0 = blockIdx.x * 8, y0 = blockIdx.y * 8;
  const int z = blockIdx.z;
  const bool isbg = z < 2;
  const int b = z & 1;

  const unsigned* xp = xpad2 + (size_t)(z * 8) * PL;
  const int oy = y0 + 3 - PAD, ox = x0 + 3 - PAD;
  for (int t = tid; t < 8 * TH * TH; t += 512) {
    int cp = t / (TH * TH);
    int r = t - cp * (TH * TH);
    int ly = r / TH, lx = r - ly * TH;
    xt2[(cp * TH + ly) * SR + lx] = xp[(size_t)cp * PL + (oy + ly) * WP + ox + lx];
  }
  __syncthreads();

  if (isbg) sim_core_bg<P>(xt2, red, memTbg, attbg + (size_t)b * (PL * 32), wv, lane, x0, y0);
  else      sim_core_tg<P>(xt2, red, memTtg, atttg2 + (size_t)(b * 4) * PL, wv, lane, x0, y0);
}

// ---------------------------------------------------------------------------
// Read conv.
// bg: MFMA f16 path. 16x16 pixel tile, 512 thr = 8 waves; wave wv owns tile
//   rows {2wv, 2wv+1} as two 16-pixel N-tiles. A = W[uv][c][m] (f16 hi+lo
//   split for ~fp32 weight accuracy), B = att halo tile in LDS (128 B/pixel
//   row, XOR bit-6 swizzle -> uniform 8 lanes/bank-quad on ds_read_b128).
//   Full K = P*P*64 accumulated fp32 -> fbg slab written directly (no
//   partials, no k_sum).
// tg: fp32 VALU path (unchanged math), c-pairs split across thread halves.
// z: 0,1 = tg b; 2,3 = bg b.
// ---------------------------------------------------------------------------
template<int P>
__global__ __launch_bounds__(512, 2) void k_read(
    const unsigned* __restrict__ attbg,    // [2][PL][64] f16
    const unsigned* __restrict__ atttg2,   // [2][4] pair-planes
    const _Float16* __restrict__ whi, const _Float16* __restrict__ wlo,
    const float* __restrict__ memRtg,
    float* __restrict__ fbgs,              // [2 b][CHW] (this scale)
    float* __restrict__ ftgs)              // [2 b][CHW] (this scale)
{
  constexpr int PAD = P / 2, TH = 16 + P - 1;
  __shared__ __align__(16) unsigned char smem[TH * TH * 128];

  const int tid = threadIdx.x;
  const int x0 = blockIdx.x * 16, y0 = blockIdx.y * 16;
  const int z = blockIdx.z;
  const int oy = y0 + 3 - PAD, ox = x0 + 3 - PAD;

  if (z >= 2) {
    // ---------------- bg MFMA path ----------------
    const int b = z - 2;
    const unsigned* ab = attbg + (size_t)b * (PL * 32);
    // stage halo: per (pixel-row, q) one 16B chunk; 128 B per pixel (64 m f16)
    for (int t = tid; t < TH * TH * 8; t += 512) {
      int row = t >> 3, q = t & 7;
      int ly = row / TH, lx = row - ly * TH;
      uint4 v = *(const uint4*)(ab + ((size_t)(oy + ly) * WP + (ox + lx)) * 32 + q * 4);
      int byt = row * 128 + ((q * 16) ^ ((row & 1) << 6));
      *(uint4*)(smem + byt) = v;
    }
    __syncthreads();

    const int wv = tid >> 6, lane = tid & 63;
    const int col = lane & 15, g = lane >> 4;
    const int row0 = wv * 2;

    f32x4 acc0 = {0.f, 0.f, 0.f, 0.f};
    f32x4 acc1 = {0.f, 0.f, 0.f, 0.f};

#pragma unroll 2
    for (int uv = 0; uv < P * P; ++uv) {
      const int u = uv / P, v = uv - u * P;
      const int r0 = (row0 + u) * TH + (col + v);
      const int r1 = r0 + TH;
#pragma unroll
      for (int ck = 0; ck < 2; ++ck) {
        size_t widx = ((size_t)uv * 16 + col) * 64 + ck * 32 + g * 8;
        f16x8 ah = *(const f16x8*)(whi + widx);
        f16x8 al = *(const f16x8*)(wlo + widx);
        int b0 = r0 * 128 + ((ck * 64) ^ ((r0 & 1) << 6)) + g * 16;
        int b1 = r1 * 128 + ((ck * 64) ^ ((r1 & 1) << 6)) + g * 16;
        f16x8 bb0 = *(const f16x8*)(smem + b0);
        f16x8 bb1 = *(const f16x8*)(smem + b1);
        acc0 = __builtin_amdgcn_mfma_f32_16x16x32_f16(ah, bb0, acc0, 0, 0, 0);
        acc1 = __builtin_amdgcn_mfma_f32_16x16x32_f16(ah, bb1, acc1, 0, 0, 0);
        acc0 = __builtin_amdgcn_mfma_f32_16x16x32_f16(al, bb0, acc0, 0, 0, 0);
        acc1 = __builtin_amdgcn_mfma_f32_16x16x32_f16(al, bb1, acc1, 0, 0, 0);
      }
    }

    // D frag: col = lane&15 (pixel x), row = g*4 + r (channel c)
#pragma unroll
    for (int t = 0; t < 2; ++t) {
      const f32x4 a = t ? acc1 : acc0;
      int gy = y0 + row0 + t, gx = x0 + col;
      int cy = min(P - 1, gy + PAD) - max(0, gy + PAD - (Hdim - 1)) + 1;
      int cx = min(P - 1, gx + PAD) - max(0, gx + PAD - (Wdim - 1)) + 1;
      float inv = 1.f / ((float)(cy * cx) + 1e-8f);
      float* outp = fbgs + (size_t)b * CHW + (size_t)(g * 4) * HWdim + gy * Wdim + gx;
#pragma unroll
      for (int r = 0; r < 4; ++r)
        outp[(size_t)r * HWdim] = a[r] * inv;
    }
  } else {
    // ---------------- tg VALU path ----------------
    const int b = z;
    constexpr int SR = 24;
    float* atf = (float*)smem;               // [8 m][TH][SR] fp32
    const unsigned* attp = atttg2 + (size_t)(b * 4) * PL;
    for (int t = tid; t < 4 * TH * TH; t += 512) {
      int mp = t / (TH * TH);
      int r = t - mp * (TH * TH);
      int ly = r / TH, lx = r - ly * TH;
      v2f v = unpack2(attp[(size_t)mp * PL + (oy + ly) * WP + ox + lx]);
      atf[((2 * mp) * TH + ly) * SR + lx]     = v.x;
      atf[((2 * mp + 1) * TH + ly) * SR + lx] = v.y;
    }
    __syncthreads();

    const int h = tid >> 8, pix = tid & 255;
    const int px = pix & 15, py = pix >> 4;
    v2f acc2[4];
#pragma unroll
    for (int q = 0; q < 4; ++q) acc2[q] = (v2f){0.f, 0.f};

    for (int ml = 0; ml < 8; ++ml) {
      const float* atm = atf + ml * TH * SR;
      const float* wbase = memRtg + (size_t)(ml * P * P) * C_CH;
#pragma unroll
      for (int u = 0; u < P; ++u) {
        const float* ar = atm + (py + u) * SR + px;
#pragma unroll
        for (int vv = 0; vv < P; ++vv) {
          float val = ar[vv];
          const v2f* wr = (const v2f*)(wbase + (u * P + vv) * C_CH) + h * 4;
          v2f vvv = {val, val};
#pragma unroll
          for (int q = 0; q < 4; ++q)
            acc2[q] = __builtin_elementwise_fma(vvv, wr[q], acc2[q]);
        }
      }
    }

    int gy = y0 + py, gx = x0 + px;
    int cy = min(P - 1, gy + PAD) - max(0, gy + PAD - (Hdim - 1)) + 1;
    int cx = min(P - 1, gx + PAD) - max(0, gx + PAD - (Wdim - 1)) + 1;
    float inv = 1.f / ((float)(cy * cx) + 1e-8f);
    float* outp = ftgs + (size_t)b * CHW + gy * Wdim + gx;
#pragma unroll
    for (int q = 0; q < 4; ++q) {
      int cp = h * 4 + q;
      outp[(size_t)(2 * cp) * HWdim]     = acc2[q].x * inv;
      outp[(size_t)(2 * cp + 1) * HWdim] = acc2[q].y * inv;
    }
  }
}

// ---------------------------------------------------------------------------
// pooled[br*32 + b*16 + c] = mean over pixels of sum over 3 scale-slabs
// ---------------------------------------------------------------------------
__global__ __launch_bounds__(256) void k_pool(const float* __restrict__ fbg,
                                              const float* __restrict__ ftg,
                                              float* __restrict__ pooled)
{
  __shared__ float red[256];
  int i = blockIdx.x;                       // 64
  int br = i >> 5, b = (i >> 4) & 1, c = i & 15;
  const float* base = (br ? ftg : fbg) + (size_t)b * CHW + (size_t)c * HWdim;
  float s = 0.f;
  for (int t = threadIdx.x; t < HWdim; t += 256)
    s += base[t] + base[(size_t)2 * CHW + t] + base[(size_t)4 * CHW + t];
  red[threadIdx.x] = s;
  __syncthreads();
  for (int off = 128; off > 0; off >>= 1) {
    if ((int)threadIdx.x < off) red[threadIdx.x] += red[threadIdx.x + off];
    __syncthreads();
  }
  if (threadIdx.x == 0) pooled[br * 32 + b * 16 + c] = red[0] * (1.f / (float)HWdim);
}

// ---------------------------------------------------------------------------
// Fusion MLP + softmax weights
// ---------------------------------------------------------------------------
__global__ __launch_bounds__(128) void k_mlp(
    const float* __restrict__ pooled,
    const float* __restrict__ w1b, const float* __restrict__ b1b,
    const float* __restrict__ w2b, const float* __restrict__ b2b,
    const float* __restrict__ w1t, const float* __restrict__ b1t,
    const float* __restrict__ w2t, const float* __restrict__ b2t,
    float* __restrict__ wt)
{
  __shared__ float hdn[Bdim][4];
  __shared__ float lg[Bdim][48];
  int t = threadIdx.x;
  for (int br = 0; br < 2; ++br) {
    const float* w1 = br ? w1t : w1b;
    const float* b1 = br ? b1t : b1b;
    const float* w2 = br ? w2t : w2b;
    const float* b2 = br ? b2t : b2b;
    if (t < 8) {
      int b = t >> 2, h = t & 3;
      float s = b1[h];
      for (int c = 0; c < C_CH; ++c) s += pooled[br * 32 + b * 16 + c] * w1[h * 16 + c];
      hdn[b][h] = fmaxf(s, 0.f);
    }
    __syncthreads();
    if (t < 96) {
      int b = t / 48, j = t - b * 48;
      float s = b2[j];
      for (int h = 0; h < 4; ++h) s += hdn[b][h] * w2[j * 4 + h];
      lg[b][j] = s;
    }
    __syncthreads();
    if (t < 32) {
      int b = t >> 4, c = t & 15;
      float l0 = lg[b][c], l1 = lg[b][16 + c], l2 = lg[b][32 + c];
      float m = fmaxf(l0, fmaxf(l1, l2));
      float e0 = __expf(l0 - m), e1 = __expf(l1 - m), e2 = __expf(l2 - m);
      float inv = 1.f / (e0 + e1 + e2);
      wt[((br * 2 + b) * 3 + 0) * 16 + c] = e0 * inv;
      wt[((br * 2 + b) * 3 + 1) * 16 + c] = e1 * inv;
      wt[((br * 2 + b) * 3 + 2) * 16 + c] = e2 * inv;
    }
    __syncthreads();
  }
}

__global__ __launch_bounds__(256) void k_out(const float* __restrict__ fbg,
                                             const float* __restrict__ ftg,
                                             const float* __restrict__ wt,
                                             float* __restrict__ out)
{
  int idx = blockIdx.x * 256 + threadIdx.x;      // 0 .. 2*PAIR_ELEMS-1
  int br  = idx >> 19;                           // PAIR_ELEMS == 2^19
  int rem = idx & ((1 << 19) - 1);               // [b][c][HW]
  int b   = rem >> 18;                           // CHW == 2^18
  int off = rem & ((1 << 18) - 1);               // [c][HW]
  int c   = off >> 14;
  const float* f = (br == 0) ? fbg : ftg;
  int wbase = (br * 2 + b) * 3;
  float acc = 0.f;
#pragma unroll
  for (int s = 0; s < 3; ++s) {
    float v = f[(size_t)(s * 2 + b) * CHW + off];
    acc = fmaf(wt[(wbase + s) * 16 + c], v, acc);
  }
  out[idx] = acc;
}

// ---------------------------------------------------------------------------
extern "C" void kernel_launch(void* const* d_in, const int* in_sizes, int n_in,
                              void* d_out, int out_size, void* d_ws, size_t ws_size,
                              hipStream_t stream)
{
  const float* bg = (const float*)d_in[0];
  const float* tg = (const float*)d_in[1];
  const float* bg_mem[3]  = {(const float*)d_in[2],  (const float*)d_in[6],  (const float*)d_in[10]};
  const float* tg_mem[3]  = {(const float*)d_in[3],  (const float*)d_in[7],  (const float*)d_in[11]};
  const float* bg_temp[3] = {(const float*)d_in[4],  (const float*)d_in[8],  (const float*)d_in[12]};
  const float* tg_temp[3] = {(const float*)d_in[5],  (const float*)d_in[9],  (const float*)d_in[13]};
  const float* bg_fc1_w = (const float*)d_in[14];
  const float* bg_fc1_b = (const float*)d_in[15];
  const float* bg_fc2_w = (const float*)d_in[16];
  const float* bg_fc2_b = (const float*)d_in[17];
  const float* tg_fc1_w = (const float*)d_in[18];
  const float* tg_fc1_b = (const float*)d_in[19];
  const float* tg_fc2_w = (const float*)d_in[20];
  const float* tg_fc2_b = (const float*)d_in[21];

  float* ws = (float*)d_ws;
  unsigned* xpad2  = (unsigned*)ws;                        // 32 * PL
  unsigned* atttg2 = xpad2 + (size_t)32 * PL;              // 8 * PL
  unsigned* attbg  = xpad2 + (size_t)40 * PL;              // 64 * PL (= 2*PL*32)
  float*    pooled = (float*)(xpad2 + (size_t)104 * PL);   // 64
  float*    wt     = pooled + 64;                          // 192
  float*    memT   = wt + 192;                             // 95,616
  float*    memRtg = memT + 95616;                         // 10,624 (tg only)
  _Float16* wbg    = (_Float16*)(memRtg + 10624);          // 169,984 halfs = 84,992 f
  float*    ftg    = memRtg + 10624 + 84992;               // 6*CHW
  float*    fbg    = ftg + (size_t)6 * CHW;                // 6*CHW

  // zero xpad2 + atttg2 + attbg borders in one shot
  hipMemsetAsync(xpad2, 0, (size_t)104 * PL * 4, stream);

  const int   Ms[6] = {64, 64, 64, 8, 8, 8};
  const int   Ps[6] = {3, 5, 7, 3, 5, 7};
  const float* mems[6]  = {bg_mem[0], bg_mem[1], bg_mem[2], tg_mem[0], tg_mem[1], tg_mem[2]};
  const float* temps[6] = {bg_temp[0], bg_temp[1], bg_temp[2], tg_temp[0], tg_temp[1], tg_temp[2]};

  float* memTs[6];
  _Float16* whis[3]; _Float16* wlos[3];
  size_t offT = 0, offW = 0;
  const size_t offRtg[3] = {0, 1152, 4352};   // 8*144, +8*400
  PrepArgs pa;
  for (int k = 0; k < 6; ++k) {
    int D = C_CH * Ps[k] * Ps[k];
    memTs[k] = memT + offT;
    if (k < 3) {
      size_t sz = (size_t)Ps[k] * Ps[k] * 16 * 64;
      whis[k] = wbg + offW;
      wlos[k] = wbg + offW + sz;
      offW += 2 * sz;
      pa.d[k] = {mems[k], temps[k], memTs[k], nullptr, whis[k], wlos[k], Ms[k], D, Ps[k]};
    } else {
      pa.d[k] = {mems[k], temps[k], memTs[k], memRtg + offRtg[k - 3], nullptr, nullptr, Ms[k], D, Ps[k]};
    }
    offT += (size_t)Ms[k] * D;
  }
  k_prep<<<dim3(196, 6), 256, 0, stream>>>(pa);
  k_padx<<<2048, 256, 0, stream>>>(bg, tg, xpad2);

  dim3 gs(16, 16, 4), bs(512);
  dim3 gr(8, 8, 4), brd(512);

  k_sim<3><<<gs, bs, 0, stream>>>(xpad2, memTs[0], memTs[3], attbg, atttg2);
  k_read<3><<<gr, brd, 0, stream>>>(attbg, atttg2, whis[0], wlos[0], memRtg + offRtg[0],
                                    fbg + (size_t)0 * 2 * CHW, ftg + (size_t)0 * 2 * CHW);
  k_sim<5><<<gs, bs, 0, stream>>>(xpad2, memTs[1], memTs[4], attbg, atttg2);
  k_read<5><<<gr, brd, 0, stream>>>(attbg, atttg2, whis[1], wlos[1], memRtg + offRtg[1],
                                    fbg + (size_t)1 * 2 * CHW, ftg + (size_t)1 * 2 * CHW);
  k_sim<7><<<gs, bs, 0, stream>>>(xpad2, memTs[2], memTs[5], attbg, atttg2);
  k_read<7><<<gr, brd, 0, stream>>>(attbg, atttg2, whis[2], wlos[2], memRtg + offRtg[2],
                                    fbg + (size_t)2 * 2 * CHW, ftg + (size_t)2 * 2 * CHW);

  k_pool<<<64, 256, 0, stream>>>(fbg, ftg, pooled);
  k_mlp<<<1, 128, 0, stream>>>(pooled, bg_fc1_w, bg_fc1_b, bg_fc2_w, bg_fc2_b,
                               tg_fc1_w, tg_fc1_b, tg_fc2_w, tg_fc2_b, wt);
  k_out<<<(2 * PAIR_ELEMS) / 256, 256, 0, stream>>>(fbg, ftg, wt, (float*)d_out);
}

// Round 2
// 289.186 us; speedup vs baseline: 1.1558x; 1.1558x over previous
//
#include <hip/hip_runtime.h>

#define C_CH 16
#define Hdim 128
#define Wdim 128
#define HWdim 16384
#define CHW (C_CH * HWdim)                 // 262144 floats: one [C][H][W] slab
#define Bdim 2
#define PAIR_ELEMS (Bdim * CHW)            // 524288

// padded canvas geometry (border 3 = max P/2, zeroed once per launch)
#define HP 134
#define WP 136
#define PL (HP * WP)                       // 18224 elements per plane

typedef float v2f __attribute__((ext_vector_type(2)));
typedef _Float16 h2 __attribute__((ext_vector_type(2)));
typedef _Float16 f16x8 __attribute__((ext_vector_type(8)));
typedef float f32x4 __attribute__((ext_vector_type(4)));

__device__ __forceinline__ v2f unpack2(unsigned u) {
  h2 h = __builtin_bit_cast(h2, u);
  return (v2f){(float)h.x, (float)h.y};
}
__device__ __forceinline__ unsigned pack2(float a, float b) {
  h2 h = {(_Float16)a, (_Float16)b};
  return __builtin_bit_cast(unsigned, h);
}

// conflict-free LDS row strides (elements) for the sim kernel
template<int P> struct SimSR { static constexpr int v = (P == 7) ? 20 : 12; };

// ---------------------------------------------------------------------------
// Prep: memT[d][m] = mem * temp/sqrt(D)   (f32, m-contiguous)         [sim]
//       tg: memR[m][u][v][c]              (f32, kernel-flipped)       [read tg]
//       bg: whi/wlo[uv][c][m]             (f16 hi+lo split)           [read bg MFMA]
// ---------------------------------------------------------------------------
struct PrepDesc {
  const float* mem;
  const float* temp;
  float* memT;
  float* memR;          // tg only (else null)
  _Float16* whi;        // bg only (else null)
  _Float16* wlo;        // bg only (else null)
  int M, D, P;
};
struct PrepArgs { PrepDesc d[6]; };

__global__ __launch_bounds__(256) void k_prep(PrepArgs a) {
  PrepDesc de = a.d[blockIdx.y];
  int n = de.M * de.D;
  int idx = blockIdx.x * 256 + threadIdx.x;
  if (idx >= n) return;
  int m = idx / de.D;
  int d = idx - m * de.D;
  float val = de.mem[idx];
  float sc = de.temp[0] / sqrtf((float)de.D);
  de.memT[d * de.M + m] = val * sc;
  int pp = de.P * de.P;
  int c = d / pp;
  int r = d - c * pp;
  int i = r / de.P;
  int j = r - i * de.P;
  if (de.memR)
    de.memR[((m * de.P + (de.P - 1 - i)) * de.P + (de.P - 1 - j)) * C_CH + c] = val;
  if (de.whi) {
    int u = de.P - 1 - i, v = de.P - 1 - j;
    size_t widx = ((size_t)(u * de.P + v) * 16 + c) * 64 + m;
    _Float16 hi = (_Float16)val;
    de.whi[widx] = hi;
    de.wlo[widx] = (_Float16)(val - (float)hi);
  }
}

// ---------------------------------------------------------------------------
// Build f16 c-pair-packed padded canvas.
// ---------------------------------------------------------------------------
__global__ __launch_bounds__(256) void k_padx(const float* __restrict__ bg,
                                              const float* __restrict__ tg,
                                              unsigned* __restrict__ xpad2)
{
  int idx = blockIdx.x * 256 + threadIdx.x;     // 32 pair-planes * HW
  int pp = idx >> 14;
  int hw = idx & (HWdim - 1);
  int y = hw >> 7, x = hw & 127;
  int z = pp >> 3, cp = pp & 7;
  const float* src = (z < 2) ? bg : tg;
  int b = z & 1;
  float a = src[((b * C_CH + 2 * cp) << 14) + hw];
  float bb = src[((b * C_CH + 2 * cp + 1) << 14) + hw];
  xpad2[(size_t)pp * PL + (y + 3) * WP + (x + 3)] = pack2(a, bb);
}

// ---------------------------------------------------------------------------
// Sim conv + softmax.
// bg -> att pixel-major m-contiguous f16: attb[(y+3)*WP+x+3][m], m=0..63
// tg -> m-pair-packed f16 padded planes
// ---------------------------------------------------------------------------
template<int P>
__device__ __forceinline__ void sim_core_bg(
    const unsigned* __restrict__ xt2, float* __restrict__ red,
    const float* __restrict__ memT, unsigned* __restrict__ attb,
    int wv, int lane, int x0, int y0)
{
  constexpr int TH = 8 + P - 1, SR = SimSR<P>::v;
  constexpr int M = 64;
  const int px = lane & 7, py = lane >> 3;
  const int m0 = wv * 8;
  v2f acc2[4];
#pragma unroll
  for (int mm = 0; mm < 4; ++mm) acc2[mm] = (v2f){0.f, 0.f};

  for (int cp = 0; cp < 8; ++cp) {
#pragma unroll
    for (int i = 0; i < P; ++i) {
#pragma unroll
      for (int j = 0; j < P; ++j) {
        v2f vp = unpack2(xt2[(cp * TH + py + i) * SR + (px + j)]);
        const v2f* w0 = (const v2f*)(memT + (size_t)((((2 * cp) * P + i) * P + j)) * M + m0);
        const v2f* w1 = (const v2f*)(memT + (size_t)((((2 * cp + 1) * P + i) * P + j)) * M + m0);
        v2f v0 = {vp.x, vp.x}, v1 = {vp.y, vp.y};
#pragma unroll
        for (int mm = 0; mm < 4; ++mm) {
          acc2[mm] = __builtin_elementwise_fma(v0, w0[mm], acc2[mm]);
          acc2[mm] = __builtin_elementwise_fma(v1, w1[mm], acc2[mm]);
        }
      }
    }
  }

  float acc[8];
#pragma unroll
  for (int mm = 0; mm < 4; ++mm) { acc[2 * mm] = acc2[mm].x; acc[2 * mm + 1] = acc2[mm].y; }

  float pm = acc[0];
#pragma unroll
  for (int mm = 1; mm < 8; ++mm) pm = fmaxf(pm, acc[mm]);
  red[wv * 64 + lane] = pm;
  __syncthreads();
  float gm = red[lane];
#pragma unroll
  for (int w = 1; w < 8; ++w) gm = fmaxf(gm, red[w * 64 + lane]);
  __syncthreads();
  float ps = 0.f;
#pragma unroll
  for (int mm = 0; mm < 8; ++mm) { acc[mm] = __expf(acc[mm] - gm); ps += acc[mm]; }
  red[wv * 64 + lane] = ps;
  __syncthreads();
  float tot = 0.f;
#pragma unroll
  for (int w = 0; w < 8; ++w) tot += red[w * 64 + lane];
  float inv = 1.f / tot;

  const int gy = y0 + py, gx = x0 + px;
  unsigned p0 = pack2(acc[0] * inv, acc[1] * inv);
  unsigned p1 = pack2(acc[2] * inv, acc[3] * inv);
  unsigned p2 = pack2(acc[4] * inv, acc[5] * inv);
  unsigned p3 = pack2(acc[6] * inv, acc[7] * inv);
  uint4 st = {p0, p1, p2, p3};
  *(uint4*)(attb + ((size_t)(gy + 3) * WP + (gx + 3)) * 32 + wv * 4) = st;
}

template<int P>
__device__ __forceinline__ void sim_core_tg(
    const unsigned* __restrict__ xt2, float* __restrict__ red,  // [8][8][64]
    const float* __restrict__ memT, unsigned* __restrict__ att2,
    int wv, int lane, int x0, int y0)
{
  constexpr int TH = 8 + P - 1, SR = SimSR<P>::v;
  constexpr int M = 8;
  const int px = lane & 7, py = lane >> 3;
  const int cp = wv;
  v2f acc2[4];
#pragma unroll
  for (int mm = 0; mm < 4; ++mm) acc2[mm] = (v2f){0.f, 0.f};

#pragma unroll
  for (int i = 0; i < P; ++i) {
#pragma unroll
    for (int j = 0; j < P; ++j) {
      v2f vp = unpack2(xt2[(cp * TH + py + i) * SR + (px + j)]);
      const v2f* w0 = (const v2f*)(memT + (size_t)((((2 * cp) * P + i) * P + j)) * M);
      const v2f* w1 = (const v2f*)(memT + (size_t)((((2 * cp + 1) * P + i) * P + j)) * M);
      v2f v0 = {vp.x, vp.x}, v1 = {vp.y, vp.y};
#pragma unroll
      for (int mm = 0; mm < 4; ++mm) {
        acc2[mm] = __builtin_elementwise_fma(v0, w0[mm], acc2[mm]);
        acc2[mm] = __builtin_elementwise_fma(v1, w1[mm], acc2[mm]);
      }
    }
  }

#pragma unroll
  for (int mm = 0; mm < 4; ++mm) {
    red[(wv * 8 + 2 * mm) * 64 + lane]     = acc2[mm].x;
    red[(wv * 8 + 2 * mm + 1) * 64 + lane] = acc2[mm].y;
  }
  __syncthreads();

  float lg[8];
#pragma unroll
  for (int m = 0; m < 8; ++m) {
    float s = red[m * 64 + lane];
#pragma unroll
    for (int w = 1; w < 8; ++w) s += red[(w * 8 + m) * 64 + lane];
    lg[m] = s;
  }
  float gm = lg[0];
#pragma unroll
  for (int m = 1; m < 8; ++m) gm = fmaxf(gm, lg[m]);
  float tot = 0.f;
#pragma unroll
  for (int m = 0; m < 8; ++m) { lg[m] = __expf(lg[m] - gm); tot += lg[m]; }
  float inv = 1.f / tot;

  const int gy = y0 + py, gx = x0 + px;
  if (wv < 4)
    att2[(size_t)wv * PL + (gy + 3) * WP + (gx + 3)] =
        pack2(lg[2 * wv] * inv, lg[2 * wv + 1] * inv);
}

template<int P>
__global__ __launch_bounds__(512, 8) void k_sim(
    const unsigned* __restrict__ xpad2,
    const float* __restrict__ memTbg, const float* __restrict__ memTtg,
    unsigned* __restrict__ attbg,    // [2][PL][64] f16 (as u32 pairs)
    unsigned* __restrict__ atttg2)   // [2][4]  pair-planes
{
  constexpr int PAD = P / 2, TH = 8 + P - 1, SR = SimSR<P>::v;
  __shared__ unsigned xt2[8 * TH * SR];
  __shared__ float red[8 * 8 * 64];

  const int tid = threadIdx.x;
  const int wv = __builtin_amdgcn_readfirstlane(tid >> 6);
  const int lane = tid & 63;
  const int x0 = blockIdx.x * 8, y0 = blockIdx.y * 8;
  const int z = blockIdx.z;
  const bool isbg = z < 2;
  const int b = z & 1;

  const unsigned* xp = xpad2 + (size_t)(z * 8) * PL;
  const int oy = y0 + 3 - PAD, ox = x0 + 3 - PAD;
  for (int t = tid; t < 8 * TH * TH; t += 512) {
    int cp = t / (TH * TH);
    int r = t - cp * (TH * TH);
    int ly = r / TH, lx = r - ly * TH;
    xt2[(cp * TH + ly) * SR + lx] = xp[(size_t)cp * PL + (oy + ly) * WP + ox + lx];
  }
  __syncthreads();

  if (isbg) sim_core_bg<P>(xt2, red, memTbg, attbg + (size_t)b * (PL * 32), wv, lane, x0, y0);
  else      sim_core_tg<P>(xt2, red, memTtg, atttg2 + (size_t)(b * 4) * PL, wv, lane, x0, y0);
}

// ---------------------------------------------------------------------------
// Read conv, K-split-over-waves MFMA form.
// Tile = 16 px wide x 8 px tall. Grid (8,16,4): z 0,1 = tg b; 2,3 = bg b.
// bg: att halo [THY][THX][64 m] f16 in LDS (XOR (hpix&7)<<4 swizzle).
//   8 waves split the uv axis (wave wv: uv = wv, wv+8, ...). Each wave
//   computes partial acc for ALL 8 pixel-row N-tiles; one weight fragment
//   pair (hi+lo, global, prefetched 1 uv ahead) feeds 32 MFMAs. LDS tree
//   (3 rounds, 32 KB, reusing dead halo) reduces 8 wave-partials; wave 0
//   applies overlap-count divisor and stores f32.
// tg: fp32 VALU path, 4 c-quarters across thread groups, SR=25 (odd stride
//   kills the 4-way aligned bank conflict of SR=24).
// ---------------------------------------------------------------------------
template<int P>
__global__ __launch_bounds__(512, 4) void k_read(
    const unsigned* __restrict__ attbg,    // [2][PL][64] f16
    const unsigned* __restrict__ atttg2,   // [2][4] pair-planes
    const _Float16* __restrict__ whi, const _Float16* __restrict__ wlo,
    const float* __restrict__ memRtg,
    float* __restrict__ fbgs,              // [2 b][CHW] (this scale)
    float* __restrict__ ftgs)              // [2 b][CHW] (this scale)
{
  constexpr int PAD = P / 2;
  constexpr int THY = 8 + P - 1, THX = 16 + P - 1;
  constexpr int HALOB = THY * THX * 128;
  constexpr int SMEMB = (HALOB > 32768) ? HALOB : 32768;
  __shared__ __align__(16) unsigned char smem[SMEMB];

  const int tid = threadIdx.x;
  const int x0 = blockIdx.x * 16, y0 = blockIdx.y * 8;
  const int z = blockIdx.z;
  const int oy = y0 + 3 - PAD, ox = x0 + 3 - PAD;

  if (z >= 2) {
    // ---------------- bg MFMA path ----------------
    const int b = z - 2;
    const unsigned* ab = attbg + (size_t)b * (PL * 32);
    // stage halo: hpix-major, 8 chunks of 16B per pixel, swizzled
    for (int t = tid; t < THY * THX * 8; t += 512) {
      int hpix = t >> 3, q = t & 7;
      int ly = hpix / THX, lx = hpix - ly * THX;
      uint4 v = *(const uint4*)(ab + ((size_t)(oy + ly) * WP + (ox + lx)) * 32 + q * 4);
      *(uint4*)(smem + hpix * 128 + ((q * 16) ^ ((hpix & 7) << 4))) = v;
    }
    __syncthreads();

    const int wv = __builtin_amdgcn_readfirstlane(tid >> 6);
    const int lane = tid & 63;
    const int col = lane & 15, g = lane >> 4;

    f32x4 acc[8];
#pragma unroll
    for (int t = 0; t < 8; ++t) acc[t] = (f32x4){0.f, 0.f, 0.f, 0.f};

    f16x8 cah[2], cal[2], nah[2], nal[2];
    auto LDA = [&](int uv, f16x8* ah, f16x8* al) {
#pragma unroll
      for (int ck = 0; ck < 2; ++ck) {
        size_t widx = ((size_t)(uv * 16 + col)) * 64 + ck * 32 + g * 8;
        ah[ck] = *(const f16x8*)(whi + widx);
        al[ck] = *(const f16x8*)(wlo + widx);
      }
    };
    LDA(wv, cah, cal);

    for (int uv = wv; uv < P * P; uv += 8) {
      if (uv + 8 < P * P) LDA(uv + 8, nah, nal);
      const int u = uv / P, v = uv - u * P;
      const int cb = col + v;
#pragma unroll
      for (int ck = 0; ck < 2; ++ck) {
#pragma unroll
        for (int t = 0; t < 8; ++t) {
          int hpix = (t + u) * THX + cb;
          f16x8 bb = *(const f16x8*)(smem + hpix * 128 +
                                     ((ck * 64 + g * 16) ^ ((hpix & 7) << 4)));
          acc[t] = __builtin_amdgcn_mfma_f32_16x16x32_f16(cah[ck], bb, acc[t], 0, 0, 0);
          acc[t] = __builtin_amdgcn_mfma_f32_16x16x32_f16(cal[ck], bb, acc[t], 0, 0, 0);
        }
      }
      cah[0] = nah[0]; cah[1] = nah[1];
      cal[0] = nal[0]; cal[1] = nal[1];
    }

    // -------- cross-wave reduction: 8 -> 4 -> 2 -> 1 (32 KB buffer) --------
    __syncthreads();                       // halo dead; reuse smem
    f32x4* buf4 = (f32x4*)smem;            // [region(4)][tile(8)][lane(64)]
    if (wv >= 4) {
#pragma unroll
      for (int t = 0; t < 8; ++t) buf4[((wv - 4) * 8 + t) * 64 + lane] = acc[t];
    }
    __syncthreads();
    if (wv < 4) {
#pragma unroll
      for (int t = 0; t < 8; ++t) acc[t] += buf4[(wv * 8 + t) * 64 + lane];
    }
    __syncthreads();
    if (wv == 2 || wv == 3) {
#pragma unroll
      for (int t = 0; t < 8; ++t) buf4[((wv - 2) * 8 + t) * 64 + lane] = acc[t];
    }
    __syncthreads();
    if (wv < 2) {
#pragma unroll
      for (int t = 0; t < 8; ++t) acc[t] += buf4[(wv * 8 + t) * 64 + lane];
    }
    __syncthreads();
    if (wv == 1) {
#pragma unroll
      for (int t = 0; t < 8; ++t) buf4[t * 64 + lane] = acc[t];
    }
    __syncthreads();
    if (wv == 0) {
#pragma unroll
      for (int t = 0; t < 8; ++t) {
        f32x4 s = acc[t] + buf4[t * 64 + lane];
        int gy = y0 + t, gx = x0 + col;
        int cy = min(P - 1, gy + PAD) - max(0, gy + PAD - (Hdim - 1)) + 1;
        int cx = min(P - 1, gx + PAD) - max(0, gx + PAD - (Wdim - 1)) + 1;
        float inv = 1.f / ((float)(cy * cx) + 1e-8f);
        float* outp = fbgs + (size_t)b * CHW + (size_t)(g * 4) * HWdim + gy * Wdim + gx;
#pragma unroll
        for (int r = 0; r < 4; ++r)
          outp[(size_t)r * HWdim] = s[r] * inv;
      }
    }
  } else {
    // ---------------- tg VALU path ----------------
    const int b = z;
    constexpr int SR = 25;
    float* atf = (float*)smem;               // [8 m][THY][SR] fp32
    const unsigned* attp = atttg2 + (size_t)(b * 4) * PL;
    for (int t = tid; t < 4 * THY * THX; t += 512) {
      int mp = t / (THY * THX);
      int r = t - mp * (THY * THX);
      int ly = r / THX, lx = r - ly * THX;
      v2f v = unpack2(attp[(size_t)mp * PL + (oy + ly) * WP + ox + lx]);
      atf[((2 * mp) * THY + ly) * SR + lx]     = v.x;
      atf[((2 * mp + 1) * THY + ly) * SR + lx] = v.y;
    }
    __syncthreads();

    const int h = tid >> 7, pix = tid & 127;
    const int px = pix & 15, py = pix >> 4;
    v2f acc2[2];
#pragma unroll
    for (int q = 0; q < 2; ++q) acc2[q] = (v2f){0.f, 0.f};

    for (int ml = 0; ml < 8; ++ml) {
      const float* atm = atf + ml * THY * SR;
      const float* wbase = memRtg + (size_t)(ml * P * P) * C_CH;
#pragma unroll
      for (int u = 0; u < P; ++u) {
        const float* ar = atm + (py + u) * SR + px;
#pragma unroll
        for (int vv = 0; vv < P; ++vv) {
          float val = ar[vv];
          const v2f* wr = (const v2f*)(wbase + (u * P + vv) * C_CH) + h * 2;
          v2f vvv = {val, val};
#pragma unroll
          for (int q = 0; q < 2; ++q)
            acc2[q] = __builtin_elementwise_fma(vvv, wr[q], acc2[q]);
        }
      }
    }

    int gy = y0 + py, gx = x0 + px;
    int cy = min(P - 1, gy + PAD) - max(0, gy + PAD - (Hdim - 1)) + 1;
    int cx = min(P - 1, gx + PAD) - max(0, gx + PAD - (Wdim - 1)) + 1;
    float inv = 1.f / ((float)(cy * cx) + 1e-8f);
    float* outp = ftgs + (size_t)b * CHW + gy * Wdim + gx;
#pragma unroll
    for (int q = 0; q < 2; ++q) {
      int cp = h * 2 + q;
      outp[(size_t)(2 * cp) * HWdim]     = acc2[q].x * inv;
      outp[(size_t)(2 * cp + 1) * HWdim] = acc2[q].y * inv;
    }
  }
}

// ---------------------------------------------------------------------------
// pooled[br*32 + b*16 + c] = mean over pixels of sum over 3 scale-slabs
// ---------------------------------------------------------------------------
__global__ __launch_bounds__(256) void k_pool(const float* __restrict__ fbg,
                                              const float* __restrict__ ftg,
                                              float* __restrict__ pooled)
{
  __shared__ float red[256];
  int i = blockIdx.x;                       // 64
  int br = i >> 5, b = (i >> 4) & 1, c = i & 15;
  const float* base = (br ? ftg : fbg) + (size_t)b * CHW + (size_t)c * HWdim;
  float s = 0.f;
  for (int t = threadIdx.x; t < HWdim; t += 256)
    s += base[t] + base[(size_t)2 * CHW + t] + base[(size_t)4 * CHW + t];
  red[threadIdx.x] = s;
  __syncthreads();
  for (int off = 128; off > 0; off >>= 1) {
    if ((int)threadIdx.x < off) red[threadIdx.x] += red[threadIdx.x + off];
    __syncthreads();
  }
  if (threadIdx.x == 0) pooled[br * 32 + b * 16 + c] = red[0] * (1.f / (float)HWdim);
}

// ---------------------------------------------------------------------------
// Fusion MLP + softmax weights
// ---------------------------------------------------------------------------
__global__ __launch_bounds__(128) void k_mlp(
    const float* __restrict__ pooled,
    const float* __restrict__ w1b, const float* __restrict__ b1b,
    const float* __restrict__ w2b, const float* __restrict__ b2b,
    const float* __restrict__ w1t, const float* __restrict__ b1t,
    const float* __restrict__ w2t, const float* __restrict__ b2t,
    float* __restrict__ wt)
{
  __shared__ float hdn[Bdim][4];
  __shared__ float lg[Bdim][48];
  int t = threadIdx.x;
  for (int br = 0; br < 2; ++br) {
    const float* w1 = br ? w1t : w1b;
    const float* b1 = br ? b1t : b1b;
    const float* w2 = br ? w2t : w2b;
    const float* b2 = br ? b2t : b2b;
    if (t < 8) {
      int b = t >> 2, h = t & 3;
      float s = b1[h];
      for (int c = 0; c < C_CH; ++c) s += pooled[br * 32 + b * 16 + c] * w1[h * 16 + c];
      hdn[b][h] = fmaxf(s, 0.f);
    }
    __syncthreads();
    if (t < 96) {
      int b = t / 48, j = t - b * 48;
      float s = b2[j];
      for (int h = 0; h < 4; ++h) s += hdn[b][h] * w2[j * 4 + h];
      lg[b][j] = s;
    }
    __syncthreads();
    if (t < 32) {
      int b = t >> 4, c = t & 15;
      float l0 = lg[b][c], l1 = lg[b][16 + c], l2 = lg[b][32 + c];
      float m = fmaxf(l0, fmaxf(l1, l2));
      float e0 = __expf(l0 - m), e1 = __expf(l1 - m), e2 = __expf(l2 - m);
      float inv = 1.f / (e0 + e1 + e2);
      wt[((br * 2 + b) * 3 + 0) * 16 + c] = e0 * inv;
      wt[((br * 2 + b) * 3 + 1) * 16 + c] = e1 * inv;
      wt[((br * 2 + b) * 3 + 2) * 16 + c] = e2 * inv;
    }
    __syncthreads();
  }
}

__global__ __launch_bounds__(256) void k_out(const float* __restrict__ fbg,
                                             const float* __restrict__ ftg,
                                             const float* __restrict__ wt,
                                             float* __restrict__ out)
{
  int idx = blockIdx.x * 256 + threadIdx.x;      // 0 .. 2*PAIR_ELEMS-1
  int br  = idx >> 19;                           // PAIR_ELEMS == 2^19
  int rem = idx & ((1 << 19) - 1);               // [b][c][HW]
  int b   = rem >> 18;                           // CHW == 2^18
  int off = rem & ((1 << 18) - 1);               // [c][HW]
  int c   = off >> 14;
  const float* f = (br == 0) ? fbg : ftg;
  int wbase = (br * 2 + b) * 3;
  float acc = 0.f;
#pragma unroll
  for (int s = 0; s < 3; ++s) {
    float v = f[(size_t)(s * 2 + b) * CHW + off];
    acc = fmaf(wt[(wbase + s) * 16 + c], v, acc);
  }
  out[idx] = acc;
}

// ---------------------------------------------------------------------------
extern "C" void kernel_launch(void* const* d_in, const int* in_sizes, int n_in,
                              void* d_out, int out_size, void* d_ws, size_t ws_size,
                              hipStream_t stream)
{
  const float* bg = (const float*)d_in[0];
  const float* tg = (const float*)d_in[1];
  const float* bg_mem[3]  = {(const float*)d_in[2],  (const float*)d_in[6],  (const float*)d_in[10]};
  const float* tg_mem[3]  = {(const float*)d_in[3],  (const float*)d_in[7],  (const float*)d_in[11]};
  const float* bg_temp[3] = {(const float*)d_in[4],  (const float*)d_in[8],  (const float*)d_in[12]};
  const float* tg_temp[3] = {(const float*)d_in[5],  (const float*)d_in[9],  (const float*)d_in[13]};
  const float* bg_fc1_w = (const float*)d_in[14];
  const float* bg_fc1_b = (const float*)d_in[15];
  const float* bg_fc2_w = (const float*)d_in[16];
  const float* bg_fc2_b = (const float*)d_in[17];
  const float* tg_fc1_w = (const float*)d_in[18];
  const float* tg_fc1_b = (const float*)d_in[19];
  const float* tg_fc2_w = (const float*)d_in[20];
  const float* tg_fc2_b = (const float*)d_in[21];

  float* ws = (float*)d_ws;
  unsigned* xpad2  = (unsigned*)ws;                        // 32 * PL
  unsigned* atttg2 = xpad2 + (size_t)32 * PL;              // 8 * PL
  unsigned* attbg  = xpad2 + (size_t)40 * PL;              // 64 * PL (= 2*PL*32)
  float*    pooled = (float*)(xpad2 + (size_t)104 * PL);   // 64
  float*    wt     = pooled + 64;                          // 192
  float*    memT   = wt + 192;                             // 95,616
  float*    memRtg = memT + 95616;                         // 10,624 (tg only)
  _Float16* wbg    = (_Float16*)(memRtg + 10624);          // 169,984 halfs = 84,992 f
  float*    ftg    = memRtg + 10624 + 84992;               // 6*CHW
  float*    fbg    = ftg + (size_t)6 * CHW;                // 6*CHW

  // zero xpad2 + atttg2 + attbg borders in one shot
  hipMemsetAsync(xpad2, 0, (size_t)104 * PL * 4, stream);

  const int   Ms[6] = {64, 64, 64, 8, 8, 8};
  const int   Ps[6] = {3, 5, 7, 3, 5, 7};
  const float* mems[6]  = {bg_mem[0], bg_mem[1], bg_mem[2], tg_mem[0], tg_mem[1], tg_mem[2]};
  const float* temps[6] = {bg_temp[0], bg_temp[1], bg_temp[2], tg_temp[0], tg_temp[1], tg_temp[2]};

  float* memTs[6];
  _Float16* whis[3]; _Float16* wlos[3];
  size_t offT = 0, offW = 0;
  const size_t offRtg[3] = {0, 1152, 4352};   // 8*144, +8*400
  PrepArgs pa;
  for (int k = 0; k < 6; ++k) {
    int D = C_CH * Ps[k] * Ps[k];
    memTs[k] = memT + offT;
    if (k < 3) {
      size_t sz = (size_t)Ps[k] * Ps[k] * 16 * 64;
      whis[k] = wbg + offW;
      wlos[k] = wbg + offW + sz;
      offW += 2 * sz;
      pa.d[k] = {mems[k], temps[k], memTs[k], nullptr, whis[k], wlos[k], Ms[k], D, Ps[k]};
    } else {
      pa.d[k] = {mems[k], temps[k], memTs[k], memRtg + offRtg[k - 3], nullptr, nullptr, Ms[k], D, Ps[k]};
    }
    offT += (size_t)Ms[k] * D;
  }
  k_prep<<<dim3(196, 6), 256, 0, stream>>>(pa);
  k_padx<<<2048, 256, 0, stream>>>(bg, tg, xpad2);

  dim3 gs(16, 16, 4), bs(512);
  dim3 gr(8, 16, 4), brd(512);

  k_sim<3><<<gs, bs, 0, stream>>>(xpad2, memTs[0], memTs[3], attbg, atttg2);
  k_read<3><<<gr, brd, 0, stream>>>(attbg, atttg2, whis[0], wlos[0], memRtg + offRtg[0],
                                    fbg + (size_t)0 * 2 * CHW, ftg + (size_t)0 * 2 * CHW);
  k_sim<5><<<gs, bs, 0, stream>>>(xpad2, memTs[1], memTs[4], attbg, atttg2);
  k_read<5><<<gr, brd, 0, stream>>>(attbg, atttg2, whis[1], wlos[1], memRtg + offRtg[1],
                                    fbg + (size_t)1 * 2 * CHW, ftg + (size_t)1 * 2 * CHW);
  k_sim<7><<<gs, bs, 0, stream>>>(xpad2, memTs[2], memTs[5], attbg, atttg2);
  k_read<7><<<gr, brd, 0, stream>>>(attbg, atttg2, whis[2], wlos[2], memRtg + offRtg[2],
                                    fbg + (size_t)2 * 2 * CHW, ftg + (size_t)2 * 2 * CHW);

  k_pool<<<64, 256, 0, stream>>>(fbg, ftg, pooled);
  k_mlp<<<1, 128, 0, stream>>>(pooled, bg_fc1_w, bg_fc1_b, bg_fc2_w, bg_fc2_b,
                               tg_fc1_w, tg_fc1_b, tg_fc2_w, tg_fc2_b, wt);
  k_out<<<(2 * PAIR_ELEMS) / 256, 256, 0, stream>>>(fbg, ftg, wt, (float*)d_out);
}

// Round 3
// 237.469 us; speedup vs baseline: 1.4075x; 1.2178x over previous
//
#include <hip/hip_runtime.h>

#define C_CH 16
#define Hdim 128
#define Wdim 128
#define HWdim 16384
#define CHW (C_CH * HWdim)                 // 262144 floats: one [C][H][W] slab
#define Bdim 2
#define PAIR_ELEMS (Bdim * CHW)            // 524288

// padded canvas geometry (border 3 = max P/2, zeroed once per launch)
#define HP 134
#define WP 136
#define PL (HP * WP)                       // 18224 elements per plane

typedef float v2f __attribute__((ext_vector_type(2)));
typedef _Float16 h2 __attribute__((ext_vector_type(2)));
typedef _Float16 f16x8 __attribute__((ext_vector_type(8)));
typedef float f32x4 __attribute__((ext_vector_type(4)));

__device__ __forceinline__ v2f unpack2(unsigned u) {
  h2 h = __builtin_bit_cast(h2, u);
  return (v2f){(float)h.x, (float)h.y};
}
__device__ __forceinline__ unsigned pack2(float a, float b) {
  h2 h = {(_Float16)a, (_Float16)b};
  return __builtin_bit_cast(unsigned, h);
}

// conflict-free LDS row strides (elements) for the tg sim kernel
template<int P> struct SimSR { static constexpr int v = (P == 7) ? 20 : 12; };

// ---------------------------------------------------------------------------
// Prep: memT[d][m] = mem * temp/sqrt(D)   (f32, m-contiguous)   [tg sim VALU]
//       tg: memR[m][u][v][c]              (f32, kernel-flipped) [read tg]
//       bg: whi/wlo[uv][c][m]             (f16 hi+lo split)     [read bg MFMA]
//       bg: simA[uvp][s][mt][row][k]      (f16 hi+lo, scaled)   [sim bg MFMA]
//           k = luv*16 + c (K=32 packs 2 uv x 16 c), row=m&15, mt=m>>4
// ---------------------------------------------------------------------------
struct PrepDesc {
  const float* mem;
  const float* temp;
  float* memT;
  float* memR;          // tg only (else null)
  _Float16* whi;        // bg only (else null)
  _Float16* wlo;        // bg only (else null)
  _Float16* simA;       // bg only (else null)
  int M, D, P;
};
struct PrepArgs { PrepDesc d[6]; };

__global__ __launch_bounds__(256) void k_prep(PrepArgs a) {
  PrepDesc de = a.d[blockIdx.y];
  int n = de.M * de.D;
  int idx = blockIdx.x * 256 + threadIdx.x;
  if (idx >= n) return;
  int m = idx / de.D;
  int d = idx - m * de.D;
  float val = de.mem[idx];
  float sc = de.temp[0] / sqrtf((float)de.D);
  de.memT[d * de.M + m] = val * sc;
  int pp = de.P * de.P;
  int c = d / pp;
  int r = d - c * pp;
  int i = r / de.P;
  int j = r - i * de.P;
  if (de.memR)
    de.memR[((m * de.P + (de.P - 1 - i)) * de.P + (de.P - 1 - j)) * C_CH + c] = val;
  if (de.whi) {
    int u = de.P - 1 - i, v = de.P - 1 - j;
    size_t widx = ((size_t)(u * de.P + v) * 16 + c) * 64 + m;
    _Float16 hi = (_Float16)val;
    de.whi[widx] = hi;
    de.wlo[widx] = (_Float16)(val - (float)hi);
  }
  if (de.simA) {
    int uv = i * de.P + j;             // NOT flipped (correlation)
    int uvp = uv >> 1, luv = uv & 1;
    int kk = luv * 16 + c;
    int mt = m >> 4, row = m & 15;
    float sv = val * sc;
    _Float16 hi2 = (_Float16)sv;
    size_t bidx = ((size_t)(uvp * 2) * 4 + mt) * 512 + row * 32 + kk;
    de.simA[bidx] = hi2;                            // s=0 (hi)
    de.simA[bidx + 2048] = (_Float16)(sv - (float)hi2);  // s=1 (lo)
  }
}

// ---------------------------------------------------------------------------
// Build f16 c-pair-packed padded canvas.
// ---------------------------------------------------------------------------
__global__ __launch_bounds__(256) void k_padx(const float* __restrict__ bg,
                                              const float* __restrict__ tg,
                                              unsigned* __restrict__ xpad2)
{
  int idx = blockIdx.x * 256 + threadIdx.x;     // 32 pair-planes * HW
  int pp = idx >> 14;
  int hw = idx & (HWdim - 1);
  int y = hw >> 7, x = hw & 127;
  int z = pp >> 3, cp = pp & 7;
  const float* src = (z < 2) ? bg : tg;
  int b = z & 1;
  float a = src[((b * C_CH + 2 * cp) << 14) + hw];
  float bb = src[((b * C_CH + 2 * cp + 1) << 14) + hw];
  xpad2[(size_t)pp * PL + (y + 3) * WP + (x + 3)] = pack2(a, bb);
}

// ---------------------------------------------------------------------------
// bg sim: MFMA. Block 256 thr (4 waves), tile 16x16 px, grid (8,8,6):
//   z = si*2 + b, si 0..2 = {P7,P5,P3} (long scale dispatched first).
// A = simA (hi+lo f16, scaled), staged per-uvp into LDS double buffer with
//   1-deep global prefetch; B = x halo pixel-major [pix][16c] f16 (32B/px).
// Wave w owns pixel rows 4w..4w+3; per uvp: 8 A-reads + 4 B-reads + 32 MFMA.
// Softmax over 64 m per pixel: lane holds 16 logits; shfl_xor(16,32) reduce.
// Output att pixel-major m-contiguous f16 (same layout k_read expects).
// ---------------------------------------------------------------------------
struct SimBgArgs {
  const unsigned* xpad2;
  const _Float16* simA[3];   // scaleidx 0..2 = P7,P5,P3
  unsigned* attbg[3];        // per scale: [2 b][PL][64 m] f16 (u32 pairs)
};

#define SIM_ABUF 15488       // halo bytes max (22*22*32); A dbuf follows

template<int P>
__device__ __forceinline__ void sim_bg_body(
    const unsigned* __restrict__ xp,     // xpad2 + b*8 planes
    const _Float16* __restrict__ simA,
    unsigned* __restrict__ attb,         // + b*PL*32 already
    unsigned char* smem, int tid, int x0, int y0)
{
  constexpr int PAD = P / 2, TH = 16 + P - 1, NPX = TH * TH;
  constexpr int NUVP = (P * P + 1) / 2;

  // ---- halo stage: [pix][16 c] f16, written as u32 c-pairs ----
  const int oy = y0 + 3 - PAD, ox = x0 + 3 - PAD;
  for (int t = tid; t < NPX * 8; t += 256) {
    int cp = t / NPX, pix = t - cp * NPX;
    int ly = pix / TH, lx = pix - ly * TH;
    *(unsigned*)(smem + pix * 32 + cp * 4) =
        xp[(size_t)cp * PL + (oy + ly) * WP + (ox + lx)];
  }

  const int w = tid >> 6, lane = tid & 63;
  const int col = lane & 15, g = lane >> 4;

  f32x4 acc[4][4];
#pragma unroll
  for (int rr = 0; rr < 4; ++rr)
#pragma unroll
    for (int mt = 0; mt < 4; ++mt) acc[rr][mt] = (f32x4){0.f, 0.f, 0.f, 0.f};

  // weight staging regs (8KB per uvp = 256 thr x 32B)
  uint4 r0, r1;
  {
    const uint4* p = (const uint4*)simA + tid;
    r0 = p[0]; r1 = p[256];
  }

  for (int uvp = 0; uvp < NUVP; ++uvp) {
    {
      uint4* q = (uint4*)(smem + SIM_ABUF + (uvp & 1) * 8192) + tid;
      q[0] = r0; q[256] = r1;
    }
    if (uvp + 1 < NUVP) {
      const uint4* p = (const uint4*)(simA + (size_t)(uvp + 1) * 4096) + tid;
      r0 = p[0]; r1 = p[256];
    }
    __syncthreads();

    const unsigned char* at = smem + SIM_ABUF + (uvp & 1) * 8192;
    f16x8 af[2][4];
#pragma unroll
    for (int s = 0; s < 2; ++s)
#pragma unroll
      for (int mt = 0; mt < 4; ++mt)
        af[s][mt] = *(const f16x8*)(at + ((s * 4 + mt) << 10) + col * 64 + g * 16);

    int uva = 2 * uvp;
    int uvb = uva + 1; if (uvb >= P * P) uvb = uva;   // padded slot (zero wts)
    const int u_ = (g >= 2) ? (uvb / P) : (uva / P);
    const int v_ = (g >= 2) ? (uvb % P) : (uva % P);

#pragma unroll
    for (int rr = 0; rr < 4; ++rr) {
      int hp = (w * 4 + rr + u_) * TH + (col + v_);
      f16x8 bb = *(const f16x8*)(smem + hp * 32 + ((g & 1) << 4));
#pragma unroll
      for (int mt = 0; mt < 4; ++mt) {
        acc[rr][mt] = __builtin_amdgcn_mfma_f32_16x16x32_f16(af[0][mt], bb, acc[rr][mt], 0, 0, 0);
        acc[rr][mt] = __builtin_amdgcn_mfma_f32_16x16x32_f16(af[1][mt], bb, acc[rr][mt], 0, 0, 0);
      }
    }
    __syncthreads();
  }

  // ---- softmax over 64 m (lane holds m = mt*16 + g*4 + r) + store ----
#pragma unroll
  for (int rr = 0; rr < 4; ++rr) {
    float l[16];
#pragma unroll
    for (int mt = 0; mt < 4; ++mt)
#pragma unroll
      for (int r = 0; r < 4; ++r) l[mt * 4 + r] = acc[rr][mt][r];
    float mx = l[0];
#pragma unroll
    for (int i = 1; i < 16; ++i) mx = fmaxf(mx, l[i]);
    mx = fmaxf(mx, __shfl_xor(mx, 16));
    mx = fmaxf(mx, __shfl_xor(mx, 32));
    float sum = 0.f;
#pragma unroll
    for (int i = 0; i < 16; ++i) { l[i] = __expf(l[i] - mx); sum += l[i]; }
    sum += __shfl_xor(sum, 16);
    sum += __shfl_xor(sum, 32);
    float inv = 1.f / sum;
    int gy = y0 + w * 4 + rr, gx = x0 + col;
    unsigned* base = attb + ((size_t)(gy + 3) * WP + (gx + 3)) * 32;
#pragma unroll
    for (int mt = 0; mt < 4; ++mt) {
      uint2 st = { pack2(l[mt * 4 + 0] * inv, l[mt * 4 + 1] * inv),
                   pack2(l[mt * 4 + 2] * inv, l[mt * 4 + 3] * inv) };
      *(uint2*)(base + mt * 8 + g * 2) = st;
    }
  }
}

__global__ __launch_bounds__(256, 3) void k_simbg(SimBgArgs a) {
  __shared__ __align__(16) unsigned char smem[SIM_ABUF + 16384];
  const int z = blockIdx.z, si = z >> 1, b = z & 1;
  const unsigned* xp = a.xpad2 + (size_t)(b * 8) * PL;
  const int x0 = blockIdx.x * 16, y0 = blockIdx.y * 16;
  if (si == 0)
    sim_bg_body<7>(xp, a.simA[0], a.attbg[0] + (size_t)b * (PL * 32), smem, threadIdx.x, x0, y0);
  else if (si == 1)
    sim_bg_body<5>(xp, a.simA[1], a.attbg[1] + (size_t)b * (PL * 32), smem, threadIdx.x, x0, y0);
  else
    sim_bg_body<3>(xp, a.simA[2], a.attbg[2] + (size_t)b * (PL * 32), smem, threadIdx.x, x0, y0);
}

// ---------------------------------------------------------------------------
// tg sim: VALU path (M=8 too small for MFMA win). 8x8 tile, 512 thr,
// grid (16,16,6): z = si*2 + b (P7 first).
// ---------------------------------------------------------------------------
template<int P>
__device__ __forceinline__ void sim_core_tg(
    const unsigned* __restrict__ xt2, float* __restrict__ red,  // [8][8][64]
    const float* __restrict__ memT, unsigned* __restrict__ att2,
    int wv, int lane, int x0, int y0)
{
  constexpr int TH = 8 + P - 1, SR = SimSR<P>::v;
  constexpr int M = 8;
  const int px = lane & 7, py = lane >> 3;
  const int cp = wv;
  v2f acc2[4];
#pragma unroll
  for (int mm = 0; mm < 4; ++mm) acc2[mm] = (v2f){0.f, 0.f};

#pragma unroll
  for (int i = 0; i < P; ++i) {
#pragma unroll
    for (int j = 0; j < P; ++j) {
      v2f vp = unpack2(xt2[(cp * TH + py + i) * SR + (px + j)]);
      const v2f* w0 = (const v2f*)(memT + (size_t)((((2 * cp) * P + i) * P + j)) * M);
      const v2f* w1 = (const v2f*)(memT + (size_t)((((2 * cp + 1) * P + i) * P + j)) * M);
      v2f v0 = {vp.x, vp.x}, v1 = {vp.y, vp.y};
#pragma unroll
      for (int mm = 0; mm < 4; ++mm) {
        acc2[mm] = __builtin_elementwise_fma(v0, w0[mm], acc2[mm]);
        acc2[mm] = __builtin_elementwise_fma(v1, w1[mm], acc2[mm]);
      }
    }
  }

#pragma unroll
  for (int mm = 0; mm < 4; ++mm) {
    red[(wv * 8 + 2 * mm) * 64 + lane]     = acc2[mm].x;
    red[(wv * 8 + 2 * mm + 1) * 64 + lane] = acc2[mm].y;
  }
  __syncthreads();

  float lg[8];
#pragma unroll
  for (int m = 0; m < 8; ++m) {
    float s = red[m * 64 + lane];
#pragma unroll
    for (int w = 1; w < 8; ++w) s += red[(w * 8 + m) * 64 + lane];
    lg[m] = s;
  }
  float gm = lg[0];
#pragma unroll
  for (int m = 1; m < 8; ++m) gm = fmaxf(gm, lg[m]);
  float tot = 0.f;
#pragma unroll
  for (int m = 0; m < 8; ++m) { lg[m] = __expf(lg[m] - gm); tot += lg[m]; }
  float inv = 1.f / tot;

  const int gy = y0 + py, gx = x0 + px;
  if (wv < 4)
    att2[(size_t)wv * PL + (gy + 3) * WP + (gx + 3)] =
        pack2(lg[2 * wv] * inv, lg[2 * wv + 1] * inv);
}

struct SimTgArgs {
  const unsigned* xpad2;
  const float* memT[3];      // scaleidx 0..2 = P7,P5,P3 (tg memT)
  unsigned* atttg[3];        // per scale: [2 b][4] pair-planes
};

template<int P>
__device__ __forceinline__ void sim_tg_scale(
    const unsigned* __restrict__ xp, const float* __restrict__ memT,
    unsigned* __restrict__ att2, unsigned* xt2, float* red,
    int tid, int x0, int y0)
{
  constexpr int PAD = P / 2, TH = 8 + P - 1, SR = SimSR<P>::v;
  const int wv = __builtin_amdgcn_readfirstlane(tid >> 6);
  const int lane = tid & 63;
  const int oy = y0 + 3 - PAD, ox = x0 + 3 - PAD;
  for (int t = tid; t < 8 * TH * TH; t += 512) {
    int cp = t / (TH * TH);
    int r = t - cp * (TH * TH);
    int ly = r / TH, lx = r - ly * TH;
    xt2[(cp * TH + ly) * SR + lx] = xp[(size_t)cp * PL + (oy + ly) * WP + ox + lx];
  }
  __syncthreads();
  sim_core_tg<P>(xt2, red, memT, att2, wv, lane, x0, y0);
}

__global__ __launch_bounds__(512, 8) void k_simtg(SimTgArgs a) {
  __shared__ unsigned xt2[2240];
  __shared__ float red[4096];
  const int z = blockIdx.z, si = z >> 1, b = z & 1;
  const unsigned* xp = a.xpad2 + (size_t)((2 + b) * 8) * PL;
  unsigned* att = a.atttg[si] + (size_t)(b * 4) * PL;
  const int x0 = blockIdx.x * 8, y0 = blockIdx.y * 8;
  if (si == 0)      sim_tg_scale<7>(xp, a.memT[0], att, xt2, red, threadIdx.x, x0, y0);
  else if (si == 1) sim_tg_scale<5>(xp, a.memT[1], att, xt2, red, threadIdx.x, x0, y0);
  else              sim_tg_scale<3>(xp, a.memT[2], att, xt2, red, threadIdx.x, x0, y0);
}

// ---------------------------------------------------------------------------
// Read conv, K-split-over-waves MFMA form (round-2 structure), fused over
// scales: grid (8,16,12), z: s = z>>2 -> {P7,P5,P3}; zz = z&3 (0,1 tg b;
// 2,3 bg b). Tile = 16 px wide x 8 px tall.
// ---------------------------------------------------------------------------
struct ReadArgs {
  const unsigned* attbg[3];
  const unsigned* atttg[3];
  const _Float16* whi[3];
  const _Float16* wlo[3];
  const float* memRtg[3];
  float* fbgs[3];
  float* ftgs[3];
};

template<int P>
__device__ __forceinline__ void read_body(
    const unsigned* __restrict__ attbg, const unsigned* __restrict__ atttg2,
    const _Float16* __restrict__ whi, const _Float16* __restrict__ wlo,
    const float* __restrict__ memRtg,
    float* __restrict__ fbgs, float* __restrict__ ftgs,
    unsigned char* smem, int tid, int zz, int x0, int y0)
{
  constexpr int PAD = P / 2;
  constexpr int THY = 8 + P - 1, THX = 16 + P - 1;
  const int oy = y0 + 3 - PAD, ox = x0 + 3 - PAD;

  if (zz >= 2) {
    // ---------------- bg MFMA path ----------------
    const int b = zz - 2;
    const unsigned* ab = attbg + (size_t)b * (PL * 32);
    for (int t = tid; t < THY * THX * 8; t += 512) {
      int hpix = t >> 3, q = t & 7;
      int ly = hpix / THX, lx = hpix - ly * THX;
      uint4 v = *(const uint4*)(ab + ((size_t)(oy + ly) * WP + (ox + lx)) * 32 + q * 4);
      *(uint4*)(smem + hpix * 128 + ((q * 16) ^ ((hpix & 7) << 4))) = v;
    }
    __syncthreads();

    const int wv = __builtin_amdgcn_readfirstlane(tid >> 6);
    const int lane = tid & 63;
    const int col = lane & 15, g = lane >> 4;

    f32x4 acc[8];
#pragma unroll
    for (int t = 0; t < 8; ++t) acc[t] = (f32x4){0.f, 0.f, 0.f, 0.f};

    f16x8 cah[2], cal[2], nah[2], nal[2];
    auto LDA = [&](int uv, f16x8* ah, f16x8* al) {
#pragma unroll
      for (int ck = 0; ck < 2; ++ck) {
        size_t widx = ((size_t)(uv * 16 + col)) * 64 + ck * 32 + g * 8;
        ah[ck] = *(const f16x8*)(whi + widx);
        al[ck] = *(const f16x8*)(wlo + widx);
      }
    };
    LDA(wv, cah, cal);

    for (int uv = wv; uv < P * P; uv += 8) {
      if (uv + 8 < P * P) LDA(uv + 8, nah, nal);
      const int u = uv / P, v = uv - u * P;
      const int cb = col + v;
#pragma unroll
      for (int ck = 0; ck < 2; ++ck) {
#pragma unroll
        for (int t = 0; t < 8; ++t) {
          int hpix = (t + u) * THX + cb;
          f16x8 bb = *(const f16x8*)(smem + hpix * 128 +
                                     ((ck * 64 + g * 16) ^ ((hpix & 7) << 4)));
          acc[t] = __builtin_amdgcn_mfma_f32_16x16x32_f16(cah[ck], bb, acc[t], 0, 0, 0);
          acc[t] = __builtin_amdgcn_mfma_f32_16x16x32_f16(cal[ck], bb, acc[t], 0, 0, 0);
        }
      }
      cah[0] = nah[0]; cah[1] = nah[1];
      cal[0] = nal[0]; cal[1] = nal[1];
    }

    // cross-wave reduction: 8 -> 4 -> 2 -> 1
    __syncthreads();
    f32x4* buf4 = (f32x4*)smem;
    if (wv >= 4) {
#pragma unroll
      for (int t = 0; t < 8; ++t) buf4[((wv - 4) * 8 + t) * 64 + lane] = acc[t];
    }
    __syncthreads();
    if (wv < 4) {
#pragma unroll
      for (int t = 0; t < 8; ++t) acc[t] += buf4[(wv * 8 + t) * 64 + lane];
    }
    __syncthreads();
    if (wv == 2 || wv == 3) {
#pragma unroll
      for (int t = 0; t < 8; ++t) buf4[((wv - 2) * 8 + t) * 64 + lane] = acc[t];
    }
    __syncthreads();
    if (wv < 2) {
#pragma unroll
      for (int t = 0; t < 8; ++t) acc[t] += buf4[(wv * 8 + t) * 64 + lane];
    }
    __syncthreads();
    if (wv == 1) {
#pragma unroll
      for (int t = 0; t < 8; ++t) buf4[t * 64 + lane] = acc[t];
    }
    __syncthreads();
    if (wv == 0) {
#pragma unroll
      for (int t = 0; t < 8; ++t) {
        f32x4 s = acc[t] + buf4[t * 64 + lane];
        int gy = y0 + t, gx = x0 + col;
        int cy = min(P - 1, gy + PAD) - max(0, gy + PAD - (Hdim - 1)) + 1;
        int cx = min(P - 1, gx + PAD) - max(0, gx + PAD - (Wdim - 1)) + 1;
        float inv = 1.f / ((float)(cy * cx) + 1e-8f);
        float* outp = fbgs + (size_t)b * CHW + (size_t)(g * 4) * HWdim + gy * Wdim + gx;
#pragma unroll
        for (int r = 0; r < 4; ++r)
          outp[(size_t)r * HWdim] = s[r] * inv;
      }
    }
  } else {
    // ---------------- tg VALU path ----------------
    const int b = zz;
    constexpr int SR = 25;
    float* atf = (float*)smem;
    const unsigned* attp = atttg2 + (size_t)(b * 4) * PL;
    for (int t = tid; t < 4 * THY * THX; t += 512) {
      int mp = t / (THY * THX);
      int r = t - mp * (THY * THX);
      int ly = r / THX, lx = r - ly * THX;
      v2f v = unpack2(attp[(size_t)mp * PL + (oy + ly) * WP + ox + lx]);
      atf[((2 * mp) * THY + ly) * SR + lx]     = v.x;
      atf[((2 * mp + 1) * THY + ly) * SR + lx] = v.y;
    }
    __syncthreads();

    const int h = tid >> 7, pix = tid & 127;
    const int px = pix & 15, py = pix >> 4;
    v2f acc2[2];
#pragma unroll
    for (int q = 0; q < 2; ++q) acc2[q] = (v2f){0.f, 0.f};

    for (int ml = 0; ml < 8; ++ml) {
      const float* atm = atf + ml * THY * SR;
      const float* wbase = memRtg + (size_t)(ml * P * P) * C_CH;
#pragma unroll
      for (int u = 0; u < P; ++u) {
        const float* ar = atm + (py + u) * SR + px;
#pragma unroll
        for (int vv = 0; vv < P; ++vv) {
          float val = ar[vv];
          const v2f* wr = (const v2f*)(wbase + (u * P + vv) * C_CH) + h * 2;
          v2f vvv = {val, val};
#pragma unroll
          for (int q = 0; q < 2; ++q)
            acc2[q] = __builtin_elementwise_fma(vvv, wr[q], acc2[q]);
        }
      }
    }

    int gy = y0 + py, gx = x0 + px;
    int cy = min(P - 1, gy + PAD) - max(0, gy + PAD - (Hdim - 1)) + 1;
    int cx = min(P - 1, gx + PAD) - max(0, gx + PAD - (Wdim - 1)) + 1;
    float inv = 1.f / ((float)(cy * cx) + 1e-8f);
    float* outp = ftgs + (size_t)b * CHW + gy * Wdim + gx;
#pragma unroll
    for (int q = 0; q < 2; ++q) {
      int cp = h * 2 + q;
      outp[(size_t)(2 * cp) * HWdim]     = acc2[q].x * inv;
      outp[(size_t)(2 * cp + 1) * HWdim] = acc2[q].y * inv;
    }
  }
}

__global__ __launch_bounds__(512, 4) void k_readall(ReadArgs a) {
  __shared__ __align__(16) unsigned char smem[39424];   // P7 bg halo (max)
  const int z = blockIdx.z, s = z >> 2, zz = z & 3;
  const int x0 = blockIdx.x * 16, y0 = blockIdx.y * 8;
  if (s == 0)
    read_body<7>(a.attbg[0], a.atttg[0], a.whi[0], a.wlo[0], a.memRtg[0],
                 a.fbgs[0], a.ftgs[0], smem, threadIdx.x, zz, x0, y0);
  else if (s == 1)
    read_body<5>(a.attbg[1], a.atttg[1], a.whi[1], a.wlo[1], a.memRtg[1],
                 a.fbgs[1], a.ftgs[1], smem, threadIdx.x, zz, x0, y0);
  else
    read_body<3>(a.attbg[2], a.atttg[2], a.whi[2], a.wlo[2], a.memRtg[2],
                 a.fbgs[2], a.ftgs[2], smem, threadIdx.x, zz, x0, y0);
}

// ---------------------------------------------------------------------------
// pooled[br*32 + b*16 + c] = mean over pixels of sum over 3 scale-slabs
// ---------------------------------------------------------------------------
__global__ __launch_bounds__(256) void k_pool(const float* __restrict__ fbg,
                                              const float* __restrict__ ftg,
                                              float* __restrict__ pooled)
{
  __shared__ float red[256];
  int i = blockIdx.x;                       // 64
  int br = i >> 5, b = (i >> 4) & 1, c = i & 15;
  const float* base = (br ? ftg : fbg) + (size_t)b * CHW + (size_t)c * HWdim;
  float s = 0.f;
  for (int t = threadIdx.x; t < HWdim; t += 256)
    s += base[t] + base[(size_t)2 * CHW + t] + base[(size_t)4 * CHW + t];
  red[threadIdx.x] = s;
  __syncthreads();
  for (int off = 128; off > 0; off >>= 1) {
    if ((int)threadIdx.x < off) red[threadIdx.x] += red[threadIdx.x + off];
    __syncthreads();
  }
  if (threadIdx.x == 0) pooled[br * 32 + b * 16 + c] = red[0] * (1.f / (float)HWdim);
}

// ---------------------------------------------------------------------------
// Fusion MLP + softmax weights
// ---------------------------------------------------------------------------
__global__ __launch_bounds__(128) void k_mlp(
    const float* __restrict__ pooled,
    const float* __restrict__ w1b, const float* __restrict__ b1b,
    const float* __restrict__ w2b, const float* __restrict__ b2b,
    const float* __restrict__ w1t, const float* __restrict__ b1t,
    const float* __restrict__ w2t, const float* __restrict__ b2t,
    float* __restrict__ wt)
{
  __shared__ float hdn[Bdim][4];
  __shared__ float lg[Bdim][48];
  int t = threadIdx.x;
  for (int br = 0; br < 2; ++br) {
    const float* w1 = br ? w1t : w1b;
    const float* b1 = br ? b1t : b1b;
    const float* w2 = br ? w2t : w2b;
    const float* b2 = br ? b2t : b2b;
    if (t < 8) {
      int b = t >> 2, h = t & 3;
      float s = b1[h];
      for (int c = 0; c < C_CH; ++c) s += pooled[br * 32 + b * 16 + c] * w1[h * 16 + c];
      hdn[b][h] = fmaxf(s, 0.f);
    }
    __syncthreads();
    if (t < 96) {
      int b = t / 48, j = t - b * 48;
      float s = b2[j];
      for (int h = 0; h < 4; ++h) s += hdn[b][h] * w2[j * 4 + h];
      lg[b][j] = s;
    }
    __syncthreads();
    if (t < 32) {
      int b = t >> 4, c = t & 15;
      float l0 = lg[b][c], l1 = lg[b][16 + c], l2 = lg[b][32 + c];
      float m = fmaxf(l0, fmaxf(l1, l2));
      float e0 = __expf(l0 - m), e1 = __expf(l1 - m), e2 = __expf(l2 - m);
      float inv = 1.f / (e0 + e1 + e2);
      wt[((br * 2 + b) * 3 + 0) * 16 + c] = e0 * inv;
      wt[((br * 2 + b) * 3 + 1) * 16 + c] = e1 * inv;
      wt[((br * 2 + b) * 3 + 2) * 16 + c] = e2 * inv;
    }
    __syncthreads();
  }
}

__global__ __launch_bounds__(256) void k_out(const float* __restrict__ fbg,
                                             const float* __restrict__ ftg,
                                             const float* __restrict__ wt,
                                             float* __restrict__ out)
{
  int idx = blockIdx.x * 256 + threadIdx.x;      // 0 .. 2*PAIR_ELEMS-1
  int br  = idx >> 19;                           // PAIR_ELEMS == 2^19
  int rem = idx & ((1 << 19) - 1);               // [b][c][HW]
  int b   = rem >> 18;                           // CHW == 2^18
  int off = rem & ((1 << 18) - 1);               // [c][HW]
  int c   = off >> 14;
  const float* f = (br == 0) ? fbg : ftg;
  int wbase = (br * 2 + b) * 3;
  float acc = 0.f;
#pragma unroll
  for (int s = 0; s < 3; ++s) {
    float v = f[(size_t)(s * 2 + b) * CHW + off];
    acc = fmaf(wt[(wbase + s) * 16 + c], v, acc);
  }
  out[idx] = acc;
}

// ---------------------------------------------------------------------------
extern "C" void kernel_launch(void* const* d_in, const int* in_sizes, int n_in,
                              void* d_out, int out_size, void* d_ws, size_t ws_size,
                              hipStream_t stream)
{
  const float* bg = (const float*)d_in[0];
  const float* tg = (const float*)d_in[1];
  const float* bg_mem[3]  = {(const float*)d_in[2],  (const float*)d_in[6],  (const float*)d_in[10]};
  const float* tg_mem[3]  = {(const float*)d_in[3],  (const float*)d_in[7],  (const float*)d_in[11]};
  const float* bg_temp[3] = {(const float*)d_in[4],  (const float*)d_in[8],  (const float*)d_in[12]};
  const float* tg_temp[3] = {(const float*)d_in[5],  (const float*)d_in[9],  (const float*)d_in[13]};
  const float* bg_fc1_w = (const float*)d_in[14];
  const float* bg_fc1_b = (const float*)d_in[15];
  const float* bg_fc2_w = (const float*)d_in[16];
  const float* bg_fc2_b = (const float*)d_in[17];
  const float* tg_fc1_w = (const float*)d_in[18];
  const float* tg_fc1_b = (const float*)d_in[19];
  const float* tg_fc2_w = (const float*)d_in[20];
  const float* tg_fc2_b = (const float*)d_in[21];

  float* ws = (float*)d_ws;
  unsigned* xpad2  = (unsigned*)ws;                        // 32 * PL
  unsigned* atttgB = xpad2 + (size_t)32 * PL;              // 3 * 8 * PL
  unsigned* attbgB = xpad2 + (size_t)56 * PL;              // 3 * 64 * PL
  float*    pooled = (float*)(xpad2 + (size_t)248 * PL);   // 64
  float*    wt     = pooled + 64;                          // 192
  float*    memT   = wt + 192;                             // 95,616
  float*    memRtg = memT + 95616;                         // 10,624
  _Float16* wbg    = (_Float16*)(memRtg + 10624);          // 169,984 halfs
  _Float16* simA   = wbg + 169984;                         // 176,128 halfs
  float*    ftg    = (float*)(simA + 176128);              // 6*CHW
  float*    fbg    = ftg + (size_t)6 * CHW;                // 6*CHW

  hipMemsetAsync(xpad2, 0, (size_t)248 * PL * 4, stream);
  hipMemsetAsync(simA, 0, (size_t)176128 * 2, stream);

  const int   Ms[6] = {64, 64, 64, 8, 8, 8};
  const int   Ps[6] = {3, 5, 7, 3, 5, 7};
  const float* mems[6]  = {bg_mem[0], bg_mem[1], bg_mem[2], tg_mem[0], tg_mem[1], tg_mem[2]};
  const float* temps[6] = {bg_temp[0], bg_temp[1], bg_temp[2], tg_temp[0], tg_temp[1], tg_temp[2]};

  float* memTs[6];
  _Float16* whis[3]; _Float16* wlos[3];
  const size_t simAoff[3] = {0, 102400, 155648};  // scaleidx 0..2 = P7,P5,P3
  size_t offT = 0, offW = 0;
  const size_t offRtg[3] = {0, 1152, 4352};       // PS order (P3,P5,P7)
  PrepArgs pa;
  for (int k = 0; k < 6; ++k) {
    int D = C_CH * Ps[k] * Ps[k];
    memTs[k] = memT + offT;
    if (k < 3) {
      size_t sz = (size_t)Ps[k] * Ps[k] * 16 * 64;
      whis[k] = wbg + offW;
      wlos[k] = wbg + offW + sz;
      offW += 2 * sz;
      int si = 2 - k;
      pa.d[k] = {mems[k], temps[k], memTs[k], nullptr, whis[k], wlos[k],
                 simA + simAoff[si], Ms[k], D, Ps[k]};
    } else {
      pa.d[k] = {mems[k], temps[k], memTs[k], memRtg + offRtg[k - 3],
                 nullptr, nullptr, nullptr, Ms[k], D, Ps[k]};
    }
    offT += (size_t)Ms[k] * D;
  }
  k_prep<<<dim3(196, 6), 256, 0, stream>>>(pa);
  k_padx<<<2048, 256, 0, stream>>>(bg, tg, xpad2);

  SimBgArgs sba;
  sba.xpad2 = xpad2;
  SimTgArgs sta;
  sta.xpad2 = xpad2;
  sta.memT[0] = memTs[5]; sta.memT[1] = memTs[4]; sta.memT[2] = memTs[3];
  ReadArgs ra;
  for (int si = 0; si < 3; ++si) {
    int p = 2 - si;                    // PS index
    sba.simA[si]  = simA + simAoff[si];
    sba.attbg[si] = attbgB + (size_t)si * 64 * PL;
    sta.atttg[si] = atttgB + (size_t)si * 8 * PL;
    ra.attbg[si]  = attbgB + (size_t)si * 64 * PL;
    ra.atttg[si]  = atttgB + (size_t)si * 8 * PL;
    ra.whi[si] = whis[p]; ra.wlo[si] = wlos[p];
    ra.memRtg[si] = memRtg + offRtg[p];
    ra.fbgs[si] = fbg + (size_t)p * 2 * CHW;
    ra.ftgs[si] = ftg + (size_t)p * 2 * CHW;
  }

  k_simbg<<<dim3(8, 8, 6), 256, 0, stream>>>(sba);
  k_simtg<<<dim3(16, 16, 6), 512, 0, stream>>>(sta);
  k_readall<<<dim3(8, 16, 12), 512, 0, stream>>>(ra);

  k_pool<<<64, 256, 0, stream>>>(fbg, ftg, pooled);
  k_mlp<<<1, 128, 0, stream>>>(pooled, bg_fc1_w, bg_fc1_b, bg_fc2_w, bg_fc2_b,
                               tg_fc1_w, tg_fc1_b, tg_fc2_w, tg_fc2_b, wt);
  k_out<<<(2 * PAIR_ELEMS) / 256, 256, 0, stream>>>(fbg, ftg, wt, (float*)d_out);
}